// Round 3
// baseline (146.417 us; speedup 1.0000x reference)
//
#include <hip/hip_runtime.h>
#include <hip/hip_bf16.h>
#include <math.h>

// Problem constants (B, Cin, Cmid, H, W) = (2, 256, 128, 112, 112), R=3
constexpr int B    = 2;
constexpr int CIN  = 256;
constexpr int CMID = 128;
constexpr int H    = 112;
constexpr int W    = 112;
constexpr int HW   = H * W;        // 12544
constexpr int NPIX = B * HW;       // 25088
constexpr int RAD  = 3;
constexpr int KS   = 7;
constexpr int DD   = 49;

typedef __attribute__((ext_vector_type(8))) short  short8;   // 8 bf16 (4 VGPR)
typedef __attribute__((ext_vector_type(4))) float  float4v;  // MFMA C/D

// RNE fp32-pair -> packed bf16x2 via v_cvt_pk_bf16_f32 (compiler-lowered)
__device__ __forceinline__ unsigned pkbf(float a, float b) {
    __hip_bfloat162 h = __float22bfloat162_rn(make_float2(a, b));
    union { __hip_bfloat162 h2; unsigned u; } c;
    c.h2 = h;
    return c.u;
}

// ---------------------------------------------------------------------------
// Kernel 1: q = l2norm(Wq @ phi_cur), k = l2norm(Wk @ phi_rnd)  via bf16 MFMA.
// 32-PIXEL tiles (was 64): 1568 blocks -> 6.125/CU (tail waste 31%->14%),
// LDS 17.4 KB -> __launch_bounds__(256,4) = 4 resident blocks/CU for
// stage/compute interleave across blocks.
// phi tile staged pixel-major bf16, ROW STRIDE 264 shorts, column XOR-swizzle
// ((row>>3)&3)<<4 (shorts): staging b32 writes 2-way (free), frag b128 reads
// bank-balanced (8 lanes/group, derived).
// W is consumed as f32 with cvt_pk at use; next-kc W rows are SOFTWARE
// PREFETCHED (1-deep) so the ~200cyc L2 latency hides under MFMA+cvt.
// prep kernel is GONE: block (0,0) writes the padded Wv table (wvp) as a
// side job before its barrier.
// ---------------------------------------------------------------------------
constexpr int PIX  = 32;            // pixels per block
constexpr int PSTR = 264;           // shorts per pixel row in pt

__global__ __launch_bounds__(256, 4) void proj_mfma(
    const float* __restrict__ phi_cur, const float* __restrict__ phi_rnd,
    const float* __restrict__ Wq, const float* __restrict__ Wk,
    const float* __restrict__ Wv,
    unsigned short* __restrict__ q_ws, unsigned short* __restrict__ k_ws,
    float* __restrict__ wvp)
{
    __shared__ unsigned short pt[PIX * PSTR];  // 16,896 B  pixel-major bf16
    __shared__ float red[4][PIX];              //     512 B

    const int tid  = threadIdx.x;
    const int lane = tid & 63;
    const int wv   = __builtin_amdgcn_readfirstlane(tid >> 6);
    const int t    = blockIdx.y;                    // 0 -> q, 1 -> k

    const float* __restrict__ phi = t ? phi_rnd : phi_cur;
    const float* __restrict__ Wf  = t ? Wk : Wq;
    unsigned short* __restrict__ outp = t ? k_ws : q_ws;

    const int pgb = blockIdx.x * PIX;               // 32-aligned, no b crossing
    const int b   = pgb / HW;
    const int pim = pgb % HW;
    const float* pbase = phi + (size_t)b * CIN * HW + pim;

    // ---- stage phi tile: 4 passes; thread -> (channel-pair, pixel-quad) ----
#pragma unroll
    for (int pass = 0; pass < 4; ++pass) {
        const int idx = pass * 256 + tid;
        const int cp  = idx >> 3;          // channel pair 0..127
        const int pq  = idx & 7;           // pixel quad  0..7
        const int c0  = cp * 2;
        const int swz = ((pq >> 1) & 3) << 4;        // == ((row>>3)&3)<<4
        const float4 va = *(const float4*)(pbase + (size_t)c0 * HW + pq * 4);
        const float4 vb = *(const float4*)(pbase + (size_t)(c0 + 1) * HW + pq * 4);
        const int col = c0 ^ swz;
        *(unsigned*)(pt + (pq * 4 + 0) * PSTR + col) = pkbf(va.x, vb.x);
        *(unsigned*)(pt + (pq * 4 + 1) * PSTR + col) = pkbf(va.y, vb.y);
        *(unsigned*)(pt + (pq * 4 + 2) * PSTR + col) = pkbf(va.z, vb.z);
        *(unsigned*)(pt + (pq * 4 + 3) * PSTR + col) = pkbf(va.w, vb.w);
    }

    // ---- side job (one block): padded Wv -> wvp [49][52], before barrier ----
    if (blockIdx.x == 0 && t == 0) {
        for (int idx = tid; idx < DD * 52; idx += 256) {
            const int r = idx / 52, c = idx % 52;
            wvp[idx] = (c < DD) ? Wv[r * DD + c] : 0.f;
        }
    }

    __syncthreads();

    // ---- MFMA: 2 out-tiles x 2 pixel-tiles x K=256; W prefetched 1-deep ----
    const int m = lane & 15, quad = lane >> 4;
    const float* wr0 = Wf + (size_t)(wv * 32 + m) * CIN + quad * 8;
    const float* wr1 = Wf + (size_t)(wv * 32 + 16 + m) * CIN + quad * 8;

    float4 c0a = *(const float4*)(wr0);
    float4 c0b = *(const float4*)(wr0 + 4);
    float4 c1a = *(const float4*)(wr1);
    float4 c1b = *(const float4*)(wr1 + 4);

    float4v acc[2][2];
#pragma unroll
    for (int ot = 0; ot < 2; ++ot)
#pragma unroll
        for (int nt = 0; nt < 2; ++nt) acc[ot][nt] = (float4v)0.f;

#pragma unroll
    for (int kc = 0; kc < 8; ++kc) {
        const int kn = (kc < 7) ? kc + 1 : 7;        // branchless prefetch idx
        const float4 n0a = *(const float4*)(wr0 + kn * 32);
        const float4 n0b = *(const float4*)(wr0 + kn * 32 + 4);
        const float4 n1a = *(const float4*)(wr1 + kn * 32);
        const float4 n1b = *(const float4*)(wr1 + kn * 32 + 4);

        short8 bfr[2];
#pragma unroll
        for (int nt = 0; nt < 2; ++nt) {
            const int row = nt * 16 + m;
            const int col = (kc * 32 + quad * 8) ^ (((row >> 3) & 3) << 4);
            bfr[nt] = *(const short8*)(pt + row * PSTR + col);
        }

        union { short8 s; unsigned u[4]; } a0, a1;
        a0.u[0] = pkbf(c0a.x, c0a.y); a0.u[1] = pkbf(c0a.z, c0a.w);
        a0.u[2] = pkbf(c0b.x, c0b.y); a0.u[3] = pkbf(c0b.z, c0b.w);
        a1.u[0] = pkbf(c1a.x, c1a.y); a1.u[1] = pkbf(c1a.z, c1a.w);
        a1.u[2] = pkbf(c1b.x, c1b.y); a1.u[3] = pkbf(c1b.z, c1b.w);

#pragma unroll
        for (int nt = 0; nt < 2; ++nt) {
            acc[0][nt] = __builtin_amdgcn_mfma_f32_16x16x32_bf16(a0.s, bfr[nt], acc[0][nt], 0, 0, 0);
            acc[1][nt] = __builtin_amdgcn_mfma_f32_16x16x32_bf16(a1.s, bfr[nt], acc[1][nt], 0, 0, 0);
        }
        c0a = n0a; c0b = n0b; c1a = n1a; c1b = n1b;
    }

    // ---- per-pixel L2 norm: C layout col=lane&15=pixel, row=quad*4+reg=och
#pragma unroll
    for (int nt = 0; nt < 2; ++nt) {
        float ss = 0.f;
#pragma unroll
        for (int ot = 0; ot < 2; ++ot)
#pragma unroll
            for (int r = 0; r < 4; ++r)
                ss = fmaf(acc[ot][nt][r], acc[ot][nt][r], ss);
        ss += __shfl_xor(ss, 16, 64);
        ss += __shfl_xor(ss, 32, 64);
        if (quad == 0) red[wv][nt * 16 + m] = ss;
    }
    __syncthreads();

    float inv[2];
#pragma unroll
    for (int nt = 0; nt < 2; ++nt) {
        const int px = nt * 16 + m;
        const float tot = red[0][px] + red[1][px] + red[2][px] + red[3][px];
        inv[nt] = 1.f / fmaxf(sqrtf(tot), 1e-12f);
    }

    // ---- store bf16 pixel-major ----
#pragma unroll
    for (int nt = 0; nt < 2; ++nt)
#pragma unroll
        for (int ot = 0; ot < 2; ++ot) {
            uint2 st;
            st.x = pkbf(acc[ot][nt][0] * inv[nt], acc[ot][nt][1] * inv[nt]);
            st.y = pkbf(acc[ot][nt][2] * inv[nt], acc[ot][nt][3] * inv[nt]);
            *(uint2*)(outp + (size_t)(pgb + nt * 16 + m) * CMID
                      + wv * 32 + ot * 16 + quad * 4) = st;
        }
}

// ---------------------------------------------------------------------------
// Kernel 2: correlation via MFMA band-GEMM + Wv + geometry + softmax.
// Block = 16 pixels of one row.  XCD-chunked bijective block swizzle for
// k-halo L2 locality.  Phase A: stage k-tile + q-tile; GEOMETRY IS HOISTED
// here too (P_cur/P_rnd loads + dist + gamma term overlap the staging
// latency; phase C1 is then pure dot+add).  Phase B: 14 groups round-robin
// over 4 waves, band-extract into cs.  Phase C1 (lane = d): Wv row via
// 13 x b128 from padded wvp, dual-chain dot, logits -> ls (overlaid on dead
// qt; same-wave, no barrier).  Phase C2: transposed in-wave softmax.
// 2 barriers per block total.
// ---------------------------------------------------------------------------
constexpr int TILE = 16;
constexpr int COLS = TILE + 6;      // 22
constexpr int NV   = KS * COLS;     // 154 staged pixel-vectors
constexpr int KSTR = 136;           // shorts per vector in LDS (272 B)

__global__ __launch_bounds__(256) void corr_kernel(
    const unsigned short* __restrict__ q_ws, const unsigned short* __restrict__ k_ws,
    const float* __restrict__ P_cur, const float* __restrict__ P_rnd,
    const float* __restrict__ wvp, const float* __restrict__ bv,
    const float* __restrict__ gamma_p, float* __restrict__ out)
{
    __shared__ unsigned short kt[NV * KSTR];                 // 41,888 B
    __shared__ alignas(16) unsigned short qt[TILE * KSTR];   //  4,352 B (ls overlay)
    __shared__ float cs[TILE][52];                           //  3,328 B corr vectors

    const int tid  = threadIdx.x;
    const int lane = tid & 63;
    const int wv   = __builtin_amdgcn_readfirstlane(tid >> 6);

    // ---- XCD-chunked bijective swizzle: fid -> contiguous 196-block chunk --
    const int fid = (blockIdx.z * H + blockIdx.y) * (W / TILE) + blockIdx.x;
    const int swz = (fid & 7) * 196 + (fid >> 3);
    const int b   = swz / (H * (W / TILE));
    const int rem = swz % (H * (W / TILE));
    const int h   = rem / (W / TILE);
    const int w0  = (rem % (W / TILE)) * TILE;

    // ---- phase A: stage k-tile + q-tile (coalesced dwordx4; OOB zeros) ----
    const int sub  = tid & 15;
    const int vgrp = tid >> 4;          // 0..15
#pragma unroll
    for (int pass = 0; pass < 10; ++pass) {
        const int vi = pass * 16 + vgrp;
        if (vi < NV) {
            const int rr = vi / COLS;
            const int cc = vi % COLS;
            const int hh = h + rr - RAD;
            const int ww = w0 + cc - RAD;
            uint4 v = make_uint4(0, 0, 0, 0);
            if (hh >= 0 && hh < H && ww >= 0 && ww < W)
                v = *(const uint4*)(k_ws + (size_t)(b * HW + hh * W + ww) * CMID + sub * 8);
            *(uint4*)(kt + vi * KSTR + sub * 8) = v;
        }
    }
    {
        const uint4 v = *(const uint4*)(q_ws + (size_t)(b * HW + h * W + w0 + vgrp) * CMID + sub * 8);
        *(uint4*)(qt + vgrp * KSTR + sub * 8) = v;
    }

    // ---- per-lane constants + HOISTED GEOMETRY (overlap staging) ----
    const int  ld    = (lane < DD) ? lane : 0;
    const bool valid = (lane < DD);
    float4 wq4[13];
#pragma unroll
    for (int j = 0; j < 13; ++j)
        wq4[j] = *(const float4*)(wvp + ld * 52 + j * 4);
    const float bvv   = bv[ld];
    const float gamma = gamma_p[0];

    const int dy = ld / KS - RAD;
    const int dx = ld % KS - RAD;
    float geo[4];
#pragma unroll
    for (int i = 0; i < 4; ++i) {
        const int pl = wv * 4 + i;      // pixel local 0..15
        const int hn = h + dy, wn = w0 + pl + dx;
        const bool inb = valid && hn >= 0 && hn < H && wn >= 0 && wn < W;
        const float* pc = P_cur + (size_t)b * 3 * HW + (h * W + w0 + pl);
        const float cx = pc[0], cy = pc[HW], cz = pc[2 * HW];
        float rx = 0.f, ry = 0.f, rz = 0.f;
        if (inb) {
            const float* pr = P_rnd + (size_t)b * 3 * HW + (hn * W + wn);
            rx = pr[0]; ry = pr[HW]; rz = pr[2 * HW];
        }
        const float dpx = cx - rx, dpy = cy - ry, dpz = cz - rz;
        const float dist = sqrtf(fmaxf(dpx * dpx + dpy * dpy + dpz * dpz, 1e-12f));
        geo[i] = gamma * (-dist - 0.5f * fabsf(dpz));
    }

    __syncthreads();

    // zero the cs padding (cols 49..51) so phase C1's 0*pad stays 0
    if (tid < TILE * 3)
        cs[tid / 3][49 + tid % 3] = 0.f;

    // ---- phase B: MFMA band-GEMM ----
    const int m = lane & 15, quad = lane >> 4;
    for (int g = wv; g < 14; g += 4) {
        const int r  = g >> 1;
        const int nt = g & 1;
        const int vi = min(r * COLS + nt * 16 + m, NV - 1);  // clamp OOB cols
        float4v acc = (float4v)0.f;
#pragma unroll
        for (int kc = 0; kc < 4; ++kc) {
            const short8 afrag = *(const short8*)(qt + m * KSTR + kc * 32 + quad * 8);
            const short8 bfrag = *(const short8*)(kt + vi * KSTR + kc * 32 + quad * 8);
            acc = __builtin_amdgcn_mfma_f32_16x16x32_bf16(afrag, bfrag, acc, 0, 0, 0);
        }
        // band extract: D row = pixel = quad*4+reg, col cc = nt*16 + m
#pragma unroll
        for (int reg = 0; reg < 4; ++reg) {
            const int p   = quad * 4 + reg;
            const int off = nt * 16 + m - p;     // dx + RAD
            if (off >= 0 && off <= 6)
                cs[p][r * 7 + off] = acc[reg];
        }
    }
    __syncthreads();
    // qt is dead from here on -> overlay ls (16 rows x 64 f32 = 4,096 B)
    float* lsf = reinterpret_cast<float*>(qt);

    // ---- phase C1: pure dot + add (lane = d); write logit rows to ls ----
#pragma unroll
    for (int i = 0; i < 4; ++i) {
        const int pl = wv * 4 + i;      // pixel local 0..15
        float logit = -INFINITY;
        if (valid) {
            float va0 = bvv, va1 = 0.f;     // dual independent FMA chains
#pragma unroll
            for (int e4 = 0; e4 < 13; ++e4) {
                const float4 c4 = *(const float4*)&cs[pl][e4 * 4];
                const float4 w4 = wq4[e4];
                if (e4 & 1) {
                    va1 = fmaf(w4.x, c4.x, va1);
                    va1 = fmaf(w4.y, c4.y, va1);
                    va1 = fmaf(w4.z, c4.z, va1);
                    va1 = fmaf(w4.w, c4.w, va1);
                } else {
                    va0 = fmaf(w4.x, c4.x, va0);
                    va0 = fmaf(w4.y, c4.y, va0);
                    va0 = fmaf(w4.z, c4.z, va0);
                    va0 = fmaf(w4.w, c4.w, va0);
                }
            }
            logit = (va0 + va1) + geo[i];
        }
        lsf[pl * 64 + lane] = logit;    // lanes 49..63 store -inf
    }

    // ---- phase C2: transposed in-wave softmax (lane = pixel x col-quad) ----
    // Same-wave LDS write->read: compiler-ordered via lgkmcnt, no barrier.
    {
        const int pli = lane >> 4;      // 0..3 within wave
        const int dq  = lane & 15;      // column quad (cols dq*4 .. dq*4+3)
        const int pl  = wv * 4 + pli;

        const float4 v = ((const float4*)lsf)[pl * 16 + dq];

        float m4 = fmaxf(fmaxf(v.x, v.y), fmaxf(v.z, v.w));
#pragma unroll
        for (int s = 1; s < 16; s <<= 1)
            m4 = fmaxf(m4, __shfl_xor(m4, s, 64));

        const float e0 = __expf(v.x - m4);
        const float e1 = __expf(v.y - m4);
        const float e2 = __expf(v.z - m4);
        const float e3 = __expf(v.w - m4);
        float Z = (e0 + e1) + (e2 + e3);

        // dx = col%7-3, dy = col/7-3  (cols >= 49 have e == 0, values moot)
        const int c0i = dq * 4;
        float dus = 0.f, dvs = 0.f;
        {
            const float ex[4] = { e0, e1, e2, e3 };
#pragma unroll
            for (int j = 0; j < 4; ++j) {
                const int col = c0i + j;
                dus = fmaf(ex[j], (float)(col % KS - RAD), dus);
                dvs = fmaf(ex[j], (float)(col / KS - RAD), dvs);
            }
        }
#pragma unroll
        for (int s = 1; s < 16; s <<= 1) {
            Z   += __shfl_xor(Z,   s, 64);
            dus += __shfl_xor(dus, s, 64);
            dvs += __shfl_xor(dvs, s, 64);
        }

        if (dq == 0) {
            const int pg = b * HW + h * W + w0 + pl;
            const float invZ = 1.f / Z;
            out[pg]            = dus * invZ;
            out[NPIX + pg]     = dvs * invZ;
            out[2 * NPIX + pg] = invZ;       // conf = max w = exp(lmax-lmax)/Z
        }
    }
}

// ---------------------------------------------------------------------------
extern "C" void kernel_launch(void* const* d_in, const int* in_sizes, int n_in,
                              void* d_out, int out_size, void* d_ws, size_t ws_size,
                              hipStream_t stream)
{
    const float* phi_cur = (const float*)d_in[0];
    const float* phi_rnd = (const float*)d_in[1];
    const float* P_cur   = (const float*)d_in[2];
    const float* P_rnd   = (const float*)d_in[3];
    const float* Wq      = (const float*)d_in[4];
    const float* Wk      = (const float*)d_in[5];
    const float* Wv      = (const float*)d_in[6];
    const float* bv      = (const float*)d_in[7];
    const float* gm      = (const float*)d_in[8];
    float* out = (float*)d_out;

    unsigned short* ws   = (unsigned short*)d_ws;
    unsigned short* q_ws = ws;                                  // NPIX*CMID bf16
    unsigned short* k_ws = q_ws + (size_t)NPIX * CMID;          // NPIX*CMID bf16
    float*          wvp  = (float*)(k_ws + (size_t)NPIX * CMID); // 49x52 f32 (16B-aligned)

    proj_mfma<<<dim3(NPIX / PIX, 2), 256, 0, stream>>>(
        phi_cur, phi_rnd, Wq, Wk, Wv, q_ws, k_ws, wvp);

    corr_kernel<<<dim3(W / TILE, H, B), 256, 0, stream>>>(
        q_ws, k_ws, P_cur, P_rnd, wvp, bv, gm, out);
}